// Round 12
// baseline (295.963 us; speedup 1.0000x reference)
//
#include <hip/hip_runtime.h>

#define NN 50000
#define NE 800000

// ---- bf16 helpers ----
__device__ __forceinline__ float bf2f(unsigned short u) {
    union { unsigned int i; float f; } v; v.i = ((unsigned int)u) << 16; return v.f;
}
__device__ __forceinline__ unsigned short f2bf(float f) {
    union { float f; unsigned int i; } v; v.f = f;
    unsigned int r = v.i + 0x7fffu + ((v.i >> 16) & 1u);   // round-to-nearest-even
    return (unsigned short)(r >> 16);
}

// ---------------- workspace zeroing ----------------
// R11: hipMemsetAsync(400KB) ran at 9GB/s (44us!) via the runtime's small-
// size fillBuffer path. A plain wide-grid store kernel does it in ~4us.
__global__ void k_zero(float4* __restrict__ p, int n16) {
    int i = blockIdx.x * 256 + threadIdx.x;
    if (i < n16) p[i] = make_float4(0.f, 0.f, 0.f, 0.f);
}

// ---------------- CSR build ----------------

__global__ void k_count(const int* __restrict__ dst, int* __restrict__ cnt, int E) {
    int e = blockIdx.x * 256 + threadIdx.x;
    if (e < E) atomicAdd(&cnt[dst[e]], 1);
}

__global__ void k_dinv(const int* __restrict__ cnt, float* __restrict__ dinv, int N) {
    int i = blockIdx.x * 256 + threadIdx.x;
    if (i < N) dinv[i] = rsqrtf(2.0f + (float)cnt[i]);
}

__global__ void k_scanA(const int* __restrict__ cnt, int* __restrict__ row_ptr,
                        int* __restrict__ bsum, int N) {
    __shared__ int buf[256];
    int i = blockIdx.x * 256 + threadIdx.x;
    int v = (i < N) ? cnt[i] : 0;
    buf[threadIdx.x] = v;
    __syncthreads();
    for (int off = 1; off < 256; off <<= 1) {
        int t = (threadIdx.x >= off) ? buf[threadIdx.x - off] : 0;
        __syncthreads();
        buf[threadIdx.x] += t;
        __syncthreads();
    }
    if (i < N) row_ptr[i] = buf[threadIdx.x] - v;
    if (threadIdx.x == 255) bsum[blockIdx.x] = buf[255];
}

__global__ void k_scanB(int* __restrict__ bsum, int nb) {
    __shared__ int buf[256];
    int v = (threadIdx.x < nb) ? bsum[threadIdx.x] : 0;
    buf[threadIdx.x] = v;
    __syncthreads();
    for (int off = 1; off < 256; off <<= 1) {
        int t = (threadIdx.x >= off) ? buf[threadIdx.x - off] : 0;
        __syncthreads();
        buf[threadIdx.x] += t;
        __syncthreads();
    }
    if (threadIdx.x < nb) bsum[threadIdx.x] = buf[threadIdx.x] - v;
}

__global__ void k_scanC(int* __restrict__ row_ptr, const int* __restrict__ bsum,
                        int N, int E) {
    int i = blockIdx.x * 256 + threadIdx.x;
    if (i < N) row_ptr[i] += bsum[blockIdx.x];
    if (i == 0) row_ptr[N] = E;
}

// direct scatter (R10: bucket variant = 478us from 196-counter atomics;
// direct 44us / 53MB cross-XCD writeback is the accepted cost)
__global__ void k_fill(const int* __restrict__ src, const int* __restrict__ dst,
                       const float* __restrict__ dinv, const int* __restrict__ row_ptr,
                       int* __restrict__ cursor, int2* __restrict__ csr, int E) {
    int e = blockIdx.x * 256 + threadIdx.x;
    if (e >= E) return;
    int s = src[e], d = dst[e];
    int pos = row_ptr[d] + atomicAdd(&cursor[d], 1);
    float nm = dinv[s] * dinv[d];
    csr[pos] = make_int2(s, __float_as_int(nm));
}

// ---------------- GEMM layer 1: H = X @ W1 -> bf16 H ----------------
// #pragma unroll 1: full unroll spills ~230MB scratch (R1).

__global__ __launch_bounds__(256, 4) void k_gemm128(const float* __restrict__ X,
                                                    const float* __restrict__ W,
                                                    unsigned short* __restrict__ H, int N) {
    const int K = 128;
    __shared__ float Ws[K * 64];
    for (int i = threadIdx.x; i < K * 16; i += 256)
        ((float4*)Ws)[i] = ((const float4*)W)[i];
    __syncthreads();

    const int g  = threadIdx.x >> 3;
    const int c0 = (threadIdx.x & 7) * 8;
    const int r0 = blockIdx.x * 64 + g * 2;
    const int r1 = r0 + 1;
    const bool v0 = r0 < N, v1 = r1 < N;

    float a00=0,a01=0,a02=0,a03=0,a04=0,a05=0,a06=0,a07=0;
    float a10=0,a11=0,a12=0,a13=0,a14=0,a15=0,a16=0,a17=0;

    const float* x0 = X + (size_t)r0 * K;
    const float* x1 = X + (size_t)r1 * K;

#pragma unroll 1
    for (int k0 = 0; k0 < K; k0 += 4) {
        float4 xa = v0 ? *(const float4*)(x0 + k0) : make_float4(0, 0, 0, 0);
        float4 xb = v1 ? *(const float4*)(x1 + k0) : make_float4(0, 0, 0, 0);
#pragma unroll
        for (int kk = 0; kk < 4; ++kk) {
            const float xs0 = (kk == 0) ? xa.x : (kk == 1) ? xa.y : (kk == 2) ? xa.z : xa.w;
            const float xs1 = (kk == 0) ? xb.x : (kk == 1) ? xb.y : (kk == 2) ? xb.z : xb.w;
            const float* wr = &Ws[(k0 + kk) * 64 + c0];
            const float4 w0 = *(const float4*)(wr);
            const float4 w1 = *(const float4*)(wr + 4);
            a00 = fmaf(xs0, w0.x, a00); a01 = fmaf(xs0, w0.y, a01);
            a02 = fmaf(xs0, w0.z, a02); a03 = fmaf(xs0, w0.w, a03);
            a04 = fmaf(xs0, w1.x, a04); a05 = fmaf(xs0, w1.y, a05);
            a06 = fmaf(xs0, w1.z, a06); a07 = fmaf(xs0, w1.w, a07);
            a10 = fmaf(xs1, w0.x, a10); a11 = fmaf(xs1, w0.y, a11);
            a12 = fmaf(xs1, w0.z, a12); a13 = fmaf(xs1, w0.w, a13);
            a14 = fmaf(xs1, w1.x, a14); a15 = fmaf(xs1, w1.y, a15);
            a16 = fmaf(xs1, w1.z, a16); a17 = fmaf(xs1, w1.w, a17);
        }
    }

    if (v0) {
        uint4 p;
        p.x = (unsigned)f2bf(a00) | ((unsigned)f2bf(a01) << 16);
        p.y = (unsigned)f2bf(a02) | ((unsigned)f2bf(a03) << 16);
        p.z = (unsigned)f2bf(a04) | ((unsigned)f2bf(a05) << 16);
        p.w = (unsigned)f2bf(a06) | ((unsigned)f2bf(a07) << 16);
        *(uint4*)&H[(size_t)r0 * 64 + c0] = p;
    }
    if (v1) {
        uint4 p;
        p.x = (unsigned)f2bf(a10) | ((unsigned)f2bf(a11) << 16);
        p.y = (unsigned)f2bf(a12) | ((unsigned)f2bf(a13) << 16);
        p.z = (unsigned)f2bf(a14) | ((unsigned)f2bf(a15) << 16);
        p.w = (unsigned)f2bf(a16) | ((unsigned)f2bf(a17) << 16);
        *(uint4*)&H[(size_t)r1 * 64 + c0] = p;
    }
}

// ---------------- Interleaved 2-node aggregation (bf16 H, 4x16 layout) ----------------
// R11-validated: 2 nodes/wave with interleaved miss chains at 25k waves.

template <bool RELU>
__device__ __forceinline__ void agg_row2(const unsigned short* __restrict__ H,
                                         const long long* __restrict__ csr_ll,
                                         const float4& b4, float di0, float di1,
                                         int i0, int i1, int s0, int e0, int s1, int e1,
                                         int lane, int g, int c4,
                                         float4& r0, float4& r1) {
    // self-loop rows: issue first, consumed last
    ushort4 hs0 = *(const ushort4*)&H[(size_t)i0 * 64 + c4];
    ushort4 hs1 = *(const ushort4*)&H[(size_t)i1 * 64 + c4];

    // both nodes' csr chunks issued back-to-back
    int ee0 = s0 + lane, ee1 = s1 + lane;
    long long pk0 = (ee0 < e0) ? csr_ll[ee0] : 0LL;
    long long pk1 = (ee1 < e1) ? csr_ll[ee1] : 0LL;
    int px0 = (int)pk0, py0 = (int)(pk0 >> 32);
    int px1 = (int)pk1, py1 = (int)(pk1 >> 32);

    int m0 = e0 - s0; if (m0 > 64) m0 = 64;
    int m1 = e1 - s1; if (m1 > 64) m1 = 64;
    int nt0 = (m0 + 3) >> 2, nt1 = (m1 + 3) >> 2;
    int ntm = nt0 > nt1 ? nt0 : nt1;

    float4 acc0 = make_float4(0.f, 0.f, 0.f, 0.f);
    float4 acc1 = make_float4(0.f, 0.f, 0.f, 0.f);

#pragma unroll 4
    for (int t = 0; t < ntm; ++t) {      // nt0/nt1 wave-uniform -> shfl safe
        int sl = t * 4 + g;
        if (t < nt0) {
            int ss   = __shfl(px0, sl);
            float nn = __uint_as_float(__shfl(py0, sl));
            ushort4 h = *(const ushort4*)&H[(size_t)ss * 64 + c4];
            acc0.x = fmaf(bf2f(h.x), nn, acc0.x);
            acc0.y = fmaf(bf2f(h.y), nn, acc0.y);
            acc0.z = fmaf(bf2f(h.z), nn, acc0.z);
            acc0.w = fmaf(bf2f(h.w), nn, acc0.w);
        }
        if (t < nt1) {
            int ss   = __shfl(px1, sl);
            float nn = __uint_as_float(__shfl(py1, sl));
            ushort4 h = *(const ushort4*)&H[(size_t)ss * 64 + c4];
            acc1.x = fmaf(bf2f(h.x), nn, acc1.x);
            acc1.y = fmaf(bf2f(h.y), nn, acc1.y);
            acc1.z = fmaf(bf2f(h.z), nn, acc1.z);
            acc1.w = fmaf(bf2f(h.w), nn, acc1.w);
        }
    }

    // rare deg>64 spill chunks, sequential
    for (int base = s0 + 64; base < e0; base += 64) {
        int e = base + lane;
        long long pk = (e < e0) ? csr_ll[e] : 0LL;
        int px = (int)pk, py = (int)(pk >> 32);
        int m = e0 - base; if (m > 64) m = 64;
        int nt = (m + 3) >> 2;
        for (int t = 0; t < nt; ++t) {
            int sl = t * 4 + g;
            int ss = __shfl(px, sl);
            float nn = __uint_as_float(__shfl(py, sl));
            ushort4 h = *(const ushort4*)&H[(size_t)ss * 64 + c4];
            acc0.x = fmaf(bf2f(h.x), nn, acc0.x);
            acc0.y = fmaf(bf2f(h.y), nn, acc0.y);
            acc0.z = fmaf(bf2f(h.z), nn, acc0.z);
            acc0.w = fmaf(bf2f(h.w), nn, acc0.w);
        }
    }
    for (int base = s1 + 64; base < e1; base += 64) {
        int e = base + lane;
        long long pk = (e < e1) ? csr_ll[e] : 0LL;
        int px = (int)pk, py = (int)(pk >> 32);
        int m = e1 - base; if (m > 64) m = 64;
        int nt = (m + 3) >> 2;
        for (int t = 0; t < nt; ++t) {
            int sl = t * 4 + g;
            int ss = __shfl(px, sl);
            float nn = __uint_as_float(__shfl(py, sl));
            ushort4 h = *(const ushort4*)&H[(size_t)ss * 64 + c4];
            acc1.x = fmaf(bf2f(h.x), nn, acc1.x);
            acc1.y = fmaf(bf2f(h.y), nn, acc1.y);
            acc1.z = fmaf(bf2f(h.z), nn, acc1.z);
            acc1.w = fmaf(bf2f(h.w), nn, acc1.w);
        }
    }

#pragma unroll
    for (int d = 16; d <= 32; d <<= 1) {
        acc0.x += __shfl_xor(acc0.x, d); acc0.y += __shfl_xor(acc0.y, d);
        acc0.z += __shfl_xor(acc0.z, d); acc0.w += __shfl_xor(acc0.w, d);
        acc1.x += __shfl_xor(acc1.x, d); acc1.y += __shfl_xor(acc1.y, d);
        acc1.z += __shfl_xor(acc1.z, d); acc1.w += __shfl_xor(acc1.w, d);
    }

    float sa = 2.0f * di0 * di0, sb = 2.0f * di1 * di1;
    r0.x = acc0.x + sa * bf2f(hs0.x) + b4.x;
    r0.y = acc0.y + sa * bf2f(hs0.y) + b4.y;
    r0.z = acc0.z + sa * bf2f(hs0.z) + b4.z;
    r0.w = acc0.w + sa * bf2f(hs0.w) + b4.w;
    r1.x = acc1.x + sb * bf2f(hs1.x) + b4.x;
    r1.y = acc1.y + sb * bf2f(hs1.y) + b4.y;
    r1.z = acc1.z + sb * bf2f(hs1.z) + b4.z;
    r1.w = acc1.w + sb * bf2f(hs1.w) + b4.w;
    if (RELU) {
        r0.x = fmaxf(r0.x, 0.f); r0.y = fmaxf(r0.y, 0.f);
        r0.z = fmaxf(r0.z, 0.f); r0.w = fmaxf(r0.w, 0.f);
        r1.x = fmaxf(r1.x, 0.f); r1.y = fmaxf(r1.y, 0.f);
        r1.z = fmaxf(r1.z, 0.f); r1.w = fmaxf(r1.w, 0.f);
    }
}

// Fused: A = ReLU(S*H + b) for 2 nodes, then both @ Wn via LDS; Hout bf16.
// (256,6): no big register arrays (LDS tail) -> VGPR cap 85 is safe (est ~50);
// LDS 18KB x 6 blocks = 108KB/CU. Spill tripwire: WRITE_SIZE must stay 6.25MB.
// row_ptr/dinv loaded BEFORE Wl staging so the first csr round overlaps it.
__global__ __launch_bounds__(256, 6) void k_fused(const unsigned short* __restrict__ H,
                                                  const int* __restrict__ row_ptr,
                                                  const long long* __restrict__ csr_ll,
                                                  const float* __restrict__ dinv,
                                                  const float* __restrict__ bias,
                                                  const float* __restrict__ Wn,
                                                  unsigned short* __restrict__ Hout, int N) {
    __shared__ float Wl[64 * 64];
    __shared__ float Al[4][2][64];

    const int wid  = threadIdx.x >> 6;
    const int lane = threadIdx.x & 63;
    const int i0   = (blockIdx.x * 4 + wid) * 2;
    const int i1   = i0 + 1;
    const int g    = lane >> 4;
    const int c4   = (lane & 15) * 4;

    // issue row_ptr/dinv first (they head the serial miss chain)
    int idx = i0 + lane;
    int   rp = (lane <= 2) ? row_ptr[idx] : 0;
    float dv = (lane <  2) ? dinv[idx]    : 0.f;

    // stage W while rp/dv are in flight
    for (int t = threadIdx.x; t < 1024; t += 256)
        ((float4*)Wl)[t] = ((const float4*)Wn)[t];

    const float4 b4 = *(const float4*)&bias[c4];
    int s0 = __shfl(rp, 0), sm = __shfl(rp, 1), e1 = __shfl(rp, 2);
    float di0 = __shfl(dv, 0), di1 = __shfl(dv, 1);

    float4 r0, r1;
    agg_row2<true>(H, csr_ll, b4, di0, di1, i0, i1, s0, sm, sm, e1,
                   lane, g, c4, r0, r1);

    __syncthreads();   // Wl staged (and prior-iteration Al reads done)
    if (g == 0) {
        *(float4*)&Al[wid][0][c4] = r0;
        *(float4*)&Al[wid][1][c4] = r1;
    }
    __syncthreads();

    float y0 = 0.f, y1 = 0.f;
#pragma unroll 4
    for (int c = 0; c < 64; c += 4) {
        float4 a0 = *(const float4*)&Al[wid][0][c];
        float4 a1 = *(const float4*)&Al[wid][1][c];
        float w0 = Wl[(c + 0) * 64 + lane];
        float w1 = Wl[(c + 1) * 64 + lane];
        float w2 = Wl[(c + 2) * 64 + lane];
        float w3 = Wl[(c + 3) * 64 + lane];
        y0 = fmaf(a0.x, w0, y0); y0 = fmaf(a0.y, w1, y0);
        y0 = fmaf(a0.z, w2, y0); y0 = fmaf(a0.w, w3, y0);
        y1 = fmaf(a1.x, w0, y1); y1 = fmaf(a1.y, w1, y1);
        y1 = fmaf(a1.z, w2, y1); y1 = fmaf(a1.w, w3, y1);
    }
    Hout[(size_t)i0 * 64 + lane] = f2bf(y0);
    Hout[(size_t)i1 * 64 + lane] = f2bf(y1);
}

// Final layer: interleaved 2-node aggregation only (no ReLU), fp32 d_out.
// No LDS at all -> (256,8) (VGPR cap 64; agg_row2 state ~50).
__global__ __launch_bounds__(256, 8) void k_agg_last(const unsigned short* __restrict__ H,
                                                     const int* __restrict__ row_ptr,
                                                     const long long* __restrict__ csr_ll,
                                                     const float* __restrict__ dinv,
                                                     const float* __restrict__ bias,
                                                     float* __restrict__ out, int N) {
    const int wid  = threadIdx.x >> 6;
    const int lane = threadIdx.x & 63;
    const int i0   = (blockIdx.x * 4 + wid) * 2;
    const int i1   = i0 + 1;
    const int g    = lane >> 4;
    const int c4   = (lane & 15) * 4;

    const float4 b4 = *(const float4*)&bias[c4];

    int idx = i0 + lane;
    int   rp = (lane <= 2) ? row_ptr[idx] : 0;
    float dv = (lane <  2) ? dinv[idx]    : 0.f;
    int s0 = __shfl(rp, 0), sm = __shfl(rp, 1), e1 = __shfl(rp, 2);
    float di0 = __shfl(dv, 0), di1 = __shfl(dv, 1);

    float4 r0, r1;
    agg_row2<false>(H, csr_ll, b4, di0, di1, i0, i1, s0, sm, sm, e1,
                    lane, g, c4, r0, r1);
    if (g == 0) {
        *(float4*)&out[(size_t)i0 * 64 + c4] = r0;
        *(float4*)&out[(size_t)i1 * 64 + c4] = r1;
    }
}

// ---------------- launch ----------------

extern "C" void kernel_launch(void* const* d_in, const int* in_sizes, int n_in,
                              void* d_out, int out_size, void* d_ws, size_t ws_size,
                              hipStream_t stream) {
    (void)in_sizes; (void)n_in; (void)out_size; (void)ws_size;

    const float* x  = (const float*)d_in[0];
    const int*   ei = (const int*)d_in[1];
    const float* Wl[5] = {(const float*)d_in[2], (const float*)d_in[4], (const float*)d_in[6],
                          (const float*)d_in[8], (const float*)d_in[10]};
    const float* bl[5] = {(const float*)d_in[3], (const float*)d_in[5], (const float*)d_in[7],
                          (const float*)d_in[9], (const float*)d_in[11]};
    float* out = (float*)d_out;

    const int* src = ei;
    const int* dst = ei + NE;

    char* ws = (char*)d_ws;
    size_t off = 0;
    auto alloc = [&](size_t bytes) -> void* {
        void* p = ws + off;
        off += (bytes + 255) & ~(size_t)255;
        return p;
    };
    // cnt, cursor contiguous -> single zero pass
    int*   cnt      = (int*)alloc(NN * 4);
    int*   cursor   = (int*)alloc(NN * 4);
    size_t zero_bytes = (size_t)((char*)(cursor + NN) - (char*)cnt);
    int*   row_ptr  = (int*)alloc((NN + 1) * 4);
    int*   bsum     = (int*)alloc(256 * 4);
    float* dinv     = (float*)alloc(NN * 4);
    int2*  csr      = (int2*)alloc((size_t)NE * 8);
    unsigned short* Hb  = (unsigned short*)alloc((size_t)NN * 64 * 2);
    unsigned short* Hb2 = (unsigned short*)alloc((size_t)NN * 64 * 2);

    int n16 = (int)((zero_bytes + 15) / 16);
    k_zero<<<(n16 + 255) / 256, 256, 0, stream>>>((float4*)cnt, n16);

    int ebl = (NE + 255) / 256;
    int nbl = (NN + 255) / 256;
    k_count<<<ebl, 256, 0, stream>>>(dst, cnt, NE);
    k_dinv<<<nbl, 256, 0, stream>>>(cnt, dinv, NN);
    k_scanA<<<nbl, 256, 0, stream>>>(cnt, row_ptr, bsum, NN);
    k_scanB<<<1, 256, 0, stream>>>(bsum, nbl);
    k_scanC<<<nbl, 256, 0, stream>>>(row_ptr, bsum, NN, NE);
    k_fill<<<ebl, 256, 0, stream>>>(src, dst, dinv, row_ptr, cursor, csr, NE);

    const long long* csr_ll = (const long long*)csr;
    int gg = (NN + 63) / 64;
    int ga = NN / 8;    // 6250 blocks x 4 waves x 2 nodes = 50000 exactly

    // layer 1 GEMM (K=128) -> bf16 H
    k_gemm128<<<gg, 256, 0, stream>>>(x, Wl[0], Hb, NN);
    // fused: agg_t (+b_t, ReLU) then @W_{t+1} -> bf16 H
    k_fused<<<ga, 256, 0, stream>>>(Hb,  row_ptr, csr_ll, dinv, bl[0], Wl[1], Hb2, NN);
    k_fused<<<ga, 256, 0, stream>>>(Hb2, row_ptr, csr_ll, dinv, bl[1], Wl[2], Hb,  NN);
    k_fused<<<ga, 256, 0, stream>>>(Hb,  row_ptr, csr_ll, dinv, bl[2], Wl[3], Hb2, NN);
    k_fused<<<ga, 256, 0, stream>>>(Hb2, row_ptr, csr_ll, dinv, bl[3], Wl[4], Hb,  NN);
    // final aggregation (no ReLU) -> fp32 d_out
    k_agg_last<<<ga, 256, 0, stream>>>(Hb, row_ptr, csr_ll, dinv, bl[4], out, NN);
}

// Round 13
// 273.784 us; speedup vs baseline: 1.0810x; 1.0810x over previous
//
#include <hip/hip_runtime.h>

#define NN 50000
#define NE 800000

// ---- bf16 helpers ----
__device__ __forceinline__ float bf2f(unsigned short u) {
    union { unsigned int i; float f; } v; v.i = ((unsigned int)u) << 16; return v.f;
}
__device__ __forceinline__ unsigned short f2bf(float f) {
    union { float f; unsigned int i; } v; v.f = f;
    unsigned int r = v.i + 0x7fffu + ((v.i >> 16) & 1u);   // round-to-nearest-even
    return (unsigned short)(r >> 16);
}
__device__ __forceinline__ float rdlane_f(float x, int l) {
    return __uint_as_float(__builtin_amdgcn_readlane(__float_as_uint(x), l));
}

// ---------------- workspace zeroing ----------------
__global__ void k_zero(float4* __restrict__ p, int n16) {
    int i = blockIdx.x * 256 + threadIdx.x;
    if (i < n16) p[i] = make_float4(0.f, 0.f, 0.f, 0.f);
}

// ---------------- CSR build ----------------

__global__ void k_count(const int* __restrict__ dst, int* __restrict__ cnt, int E) {
    int e = blockIdx.x * 256 + threadIdx.x;
    if (e < E) atomicAdd(&cnt[dst[e]], 1);
}

__global__ void k_dinv(const int* __restrict__ cnt, float* __restrict__ dinv, int N) {
    int i = blockIdx.x * 256 + threadIdx.x;
    if (i < N) dinv[i] = rsqrtf(2.0f + (float)cnt[i]);
}

__global__ void k_scanA(const int* __restrict__ cnt, int* __restrict__ row_ptr,
                        int* __restrict__ bsum, int N) {
    __shared__ int buf[256];
    int i = blockIdx.x * 256 + threadIdx.x;
    int v = (i < N) ? cnt[i] : 0;
    buf[threadIdx.x] = v;
    __syncthreads();
    for (int off = 1; off < 256; off <<= 1) {
        int t = (threadIdx.x >= off) ? buf[threadIdx.x - off] : 0;
        __syncthreads();
        buf[threadIdx.x] += t;
        __syncthreads();
    }
    if (i < N) row_ptr[i] = buf[threadIdx.x] - v;
    if (threadIdx.x == 255) bsum[blockIdx.x] = buf[255];
}

__global__ void k_scanB(int* __restrict__ bsum, int nb) {
    __shared__ int buf[256];
    int v = (threadIdx.x < nb) ? bsum[threadIdx.x] : 0;
    buf[threadIdx.x] = v;
    __syncthreads();
    for (int off = 1; off < 256; off <<= 1) {
        int t = (threadIdx.x >= off) ? buf[threadIdx.x - off] : 0;
        __syncthreads();
        buf[threadIdx.x] += t;
        __syncthreads();
    }
    if (threadIdx.x < nb) bsum[threadIdx.x] = buf[threadIdx.x] - v;
}

__global__ void k_scanC(int* __restrict__ row_ptr, const int* __restrict__ bsum,
                        int N, int E) {
    int i = blockIdx.x * 256 + threadIdx.x;
    if (i < N) row_ptr[i] += bsum[blockIdx.x];
    if (i == 0) row_ptr[N] = E;
}

// direct scatter (R10: bucket variant = 478us from 196-counter atomics;
// direct 43us / 53MB cross-XCD writeback is the accepted cost)
__global__ void k_fill(const int* __restrict__ src, const int* __restrict__ dst,
                       const float* __restrict__ dinv, const int* __restrict__ row_ptr,
                       int* __restrict__ cursor, int2* __restrict__ csr, int E) {
    int e = blockIdx.x * 256 + threadIdx.x;
    if (e >= E) return;
    int s = src[e], d = dst[e];
    int pos = row_ptr[d] + atomicAdd(&cursor[d], 1);
    float nm = dinv[s] * dinv[d];
    csr[pos] = make_int2(s, __float_as_int(nm));
}

// ---------------- GEMM layer 1: H = X @ W1 -> bf16 H ----------------
// #pragma unroll 1: full unroll spills ~230MB scratch (R1).

__global__ __launch_bounds__(256, 4) void k_gemm128(const float* __restrict__ X,
                                                    const float* __restrict__ W,
                                                    unsigned short* __restrict__ H, int N) {
    const int K = 128;
    __shared__ float Ws[K * 64];
    for (int i = threadIdx.x; i < K * 16; i += 256)
        ((float4*)Ws)[i] = ((const float4*)W)[i];
    __syncthreads();

    const int g  = threadIdx.x >> 3;
    const int c0 = (threadIdx.x & 7) * 8;
    const int r0 = blockIdx.x * 64 + g * 2;
    const int r1 = r0 + 1;
    const bool v0 = r0 < N, v1 = r1 < N;

    float a00=0,a01=0,a02=0,a03=0,a04=0,a05=0,a06=0,a07=0;
    float a10=0,a11=0,a12=0,a13=0,a14=0,a15=0,a16=0,a17=0;

    const float* x0 = X + (size_t)r0 * K;
    const float* x1 = X + (size_t)r1 * K;

#pragma unroll 1
    for (int k0 = 0; k0 < K; k0 += 4) {
        float4 xa = v0 ? *(const float4*)(x0 + k0) : make_float4(0, 0, 0, 0);
        float4 xb = v1 ? *(const float4*)(x1 + k0) : make_float4(0, 0, 0, 0);
#pragma unroll
        for (int kk = 0; kk < 4; ++kk) {
            const float xs0 = (kk == 0) ? xa.x : (kk == 1) ? xa.y : (kk == 2) ? xa.z : xa.w;
            const float xs1 = (kk == 0) ? xb.x : (kk == 1) ? xb.y : (kk == 2) ? xb.z : xb.w;
            const float* wr = &Ws[(k0 + kk) * 64 + c0];
            const float4 w0 = *(const float4*)(wr);
            const float4 w1 = *(const float4*)(wr + 4);
            a00 = fmaf(xs0, w0.x, a00); a01 = fmaf(xs0, w0.y, a01);
            a02 = fmaf(xs0, w0.z, a02); a03 = fmaf(xs0, w0.w, a03);
            a04 = fmaf(xs0, w1.x, a04); a05 = fmaf(xs0, w1.y, a05);
            a06 = fmaf(xs0, w1.z, a06); a07 = fmaf(xs0, w1.w, a07);
            a10 = fmaf(xs1, w0.x, a10); a11 = fmaf(xs1, w0.y, a11);
            a12 = fmaf(xs1, w0.z, a12); a13 = fmaf(xs1, w0.w, a13);
            a14 = fmaf(xs1, w1.x, a14); a15 = fmaf(xs1, w1.y, a15);
            a16 = fmaf(xs1, w1.z, a16); a17 = fmaf(xs1, w1.w, a17);
        }
    }

    if (v0) {
        uint4 p;
        p.x = (unsigned)f2bf(a00) | ((unsigned)f2bf(a01) << 16);
        p.y = (unsigned)f2bf(a02) | ((unsigned)f2bf(a03) << 16);
        p.z = (unsigned)f2bf(a04) | ((unsigned)f2bf(a05) << 16);
        p.w = (unsigned)f2bf(a06) | ((unsigned)f2bf(a07) << 16);
        *(uint4*)&H[(size_t)r0 * 64 + c0] = p;
    }
    if (v1) {
        uint4 p;
        p.x = (unsigned)f2bf(a10) | ((unsigned)f2bf(a11) << 16);
        p.y = (unsigned)f2bf(a12) | ((unsigned)f2bf(a13) << 16);
        p.z = (unsigned)f2bf(a14) | ((unsigned)f2bf(a15) << 16);
        p.w = (unsigned)f2bf(a16) | ((unsigned)f2bf(a17) << 16);
        *(uint4*)&H[(size_t)r1 * 64 + c0] = p;
    }
}

// ---------------- Interleaved 2-node aggregation (bf16 H, 4x16 layout) ----------------
// R11-validated: 2 nodes/wave with interleaved miss chains at 25k waves.

template <bool RELU>
__device__ __forceinline__ void agg_row2(const unsigned short* __restrict__ H,
                                         const long long* __restrict__ csr_ll,
                                         const float4& b4, float di0, float di1,
                                         int i0, int i1, int s0, int e0, int s1, int e1,
                                         int lane, int g, int c4,
                                         float4& r0, float4& r1) {
    // self-loop rows: issue first, consumed last
    ushort4 hs0 = *(const ushort4*)&H[(size_t)i0 * 64 + c4];
    ushort4 hs1 = *(const ushort4*)&H[(size_t)i1 * 64 + c4];

    // both nodes' csr chunks issued back-to-back
    int ee0 = s0 + lane, ee1 = s1 + lane;
    long long pk0 = (ee0 < e0) ? csr_ll[ee0] : 0LL;
    long long pk1 = (ee1 < e1) ? csr_ll[ee1] : 0LL;
    int px0 = (int)pk0, py0 = (int)(pk0 >> 32);
    int px1 = (int)pk1, py1 = (int)(pk1 >> 32);

    int m0 = e0 - s0; if (m0 > 64) m0 = 64;
    int m1 = e1 - s1; if (m1 > 64) m1 = 64;
    int nt0 = (m0 + 3) >> 2, nt1 = (m1 + 3) >> 2;
    int ntm = nt0 > nt1 ? nt0 : nt1;

    float4 acc0 = make_float4(0.f, 0.f, 0.f, 0.f);
    float4 acc1 = make_float4(0.f, 0.f, 0.f, 0.f);

#pragma unroll 4
    for (int t = 0; t < ntm; ++t) {      // nt0/nt1 wave-uniform -> shfl safe
        int sl = t * 4 + g;
        if (t < nt0) {
            int ss   = __shfl(px0, sl);
            float nn = __uint_as_float(__shfl(py0, sl));
            ushort4 h = *(const ushort4*)&H[(size_t)ss * 64 + c4];
            acc0.x = fmaf(bf2f(h.x), nn, acc0.x);
            acc0.y = fmaf(bf2f(h.y), nn, acc0.y);
            acc0.z = fmaf(bf2f(h.z), nn, acc0.z);
            acc0.w = fmaf(bf2f(h.w), nn, acc0.w);
        }
        if (t < nt1) {
            int ss   = __shfl(px1, sl);
            float nn = __uint_as_float(__shfl(py1, sl));
            ushort4 h = *(const ushort4*)&H[(size_t)ss * 64 + c4];
            acc1.x = fmaf(bf2f(h.x), nn, acc1.x);
            acc1.y = fmaf(bf2f(h.y), nn, acc1.y);
            acc1.z = fmaf(bf2f(h.z), nn, acc1.z);
            acc1.w = fmaf(bf2f(h.w), nn, acc1.w);
        }
    }

    // rare deg>64 spill chunks, sequential
    for (int base = s0 + 64; base < e0; base += 64) {
        int e = base + lane;
        long long pk = (e < e0) ? csr_ll[e] : 0LL;
        int px = (int)pk, py = (int)(pk >> 32);
        int m = e0 - base; if (m > 64) m = 64;
        int nt = (m + 3) >> 2;
        for (int t = 0; t < nt; ++t) {
            int sl = t * 4 + g;
            int ss = __shfl(px, sl);
            float nn = __uint_as_float(__shfl(py, sl));
            ushort4 h = *(const ushort4*)&H[(size_t)ss * 64 + c4];
            acc0.x = fmaf(bf2f(h.x), nn, acc0.x);
            acc0.y = fmaf(bf2f(h.y), nn, acc0.y);
            acc0.z = fmaf(bf2f(h.z), nn, acc0.z);
            acc0.w = fmaf(bf2f(h.w), nn, acc0.w);
        }
    }
    for (int base = s1 + 64; base < e1; base += 64) {
        int e = base + lane;
        long long pk = (e < e1) ? csr_ll[e] : 0LL;
        int px = (int)pk, py = (int)(pk >> 32);
        int m = e1 - base; if (m > 64) m = 64;
        int nt = (m + 3) >> 2;
        for (int t = 0; t < nt; ++t) {
            int sl = t * 4 + g;
            int ss = __shfl(px, sl);
            float nn = __uint_as_float(__shfl(py, sl));
            ushort4 h = *(const ushort4*)&H[(size_t)ss * 64 + c4];
            acc1.x = fmaf(bf2f(h.x), nn, acc1.x);
            acc1.y = fmaf(bf2f(h.y), nn, acc1.y);
            acc1.z = fmaf(bf2f(h.z), nn, acc1.z);
            acc1.w = fmaf(bf2f(h.w), nn, acc1.w);
        }
    }

#pragma unroll
    for (int d = 16; d <= 32; d <<= 1) {
        acc0.x += __shfl_xor(acc0.x, d); acc0.y += __shfl_xor(acc0.y, d);
        acc0.z += __shfl_xor(acc0.z, d); acc0.w += __shfl_xor(acc0.w, d);
        acc1.x += __shfl_xor(acc1.x, d); acc1.y += __shfl_xor(acc1.y, d);
        acc1.z += __shfl_xor(acc1.z, d); acc1.w += __shfl_xor(acc1.w, d);
    }

    float sa = 2.0f * di0 * di0, sb = 2.0f * di1 * di1;
    r0.x = acc0.x + sa * bf2f(hs0.x) + b4.x;
    r0.y = acc0.y + sa * bf2f(hs0.y) + b4.y;
    r0.z = acc0.z + sa * bf2f(hs0.z) + b4.z;
    r0.w = acc0.w + sa * bf2f(hs0.w) + b4.w;
    r1.x = acc1.x + sb * bf2f(hs1.x) + b4.x;
    r1.y = acc1.y + sb * bf2f(hs1.y) + b4.y;
    r1.z = acc1.z + sb * bf2f(hs1.z) + b4.z;
    r1.w = acc1.w + sb * bf2f(hs1.w) + b4.w;
    if (RELU) {
        r0.x = fmaxf(r0.x, 0.f); r0.y = fmaxf(r0.y, 0.f);
        r0.z = fmaxf(r0.z, 0.f); r0.w = fmaxf(r0.w, 0.f);
        r1.x = fmaxf(r1.x, 0.f); r1.y = fmaxf(r1.y, 0.f);
        r1.z = fmaxf(r1.z, 0.f); r1.w = fmaxf(r1.w, 0.f);
    }
}

// Fused: A = ReLU(S*H + b) for 2 nodes, then both @ Wn; Hout bf16.
// R13: ZERO LDS, ZERO barriers. A-broadcast via const-index readlane (R7-proven);
// W read from global in the tail (16KB, L2-resident, coalesced 256B/instr).
// (256,8): VGPR cap 64 (agg_row2 state ~40; R8 spill tripwire = WRITE_SIZE).
// R12 showed the 16KB Wl LDS block capped residency at 57% -> miss throughput.
__global__ __launch_bounds__(256, 8) void k_fused(const unsigned short* __restrict__ H,
                                                  const int* __restrict__ row_ptr,
                                                  const long long* __restrict__ csr_ll,
                                                  const float* __restrict__ dinv,
                                                  const float* __restrict__ bias,
                                                  const float* __restrict__ Wn,
                                                  unsigned short* __restrict__ Hout, int N) {
    const int wid  = threadIdx.x >> 6;
    const int lane = threadIdx.x & 63;
    const int i0   = (blockIdx.x * 4 + wid) * 2;
    const int i1   = i0 + 1;
    const int g    = lane >> 4;
    const int c4   = (lane & 15) * 4;

    int idx = i0 + lane;
    int   rp = (lane <= 2) ? row_ptr[idx] : 0;
    float dv = (lane <  2) ? dinv[idx]    : 0.f;

    const float4 b4 = *(const float4*)&bias[c4];
    int s0 = __shfl(rp, 0), sm = __shfl(rp, 1), e1 = __shfl(rp, 2);
    float di0 = __shfl(dv, 0), di1 = __shfl(dv, 1);

    float4 r0, r1;
    agg_row2<true>(H, csr_ll, b4, di0, di1, i0, i1, s0, sm, sm, e1,
                   lane, g, c4, r0, r1);

    // tail GEMM: channel 4q+k lives in lane q (every g group holds a copy);
    // W column read global-coalesced, shared by both nodes.
    float y0 = 0.f, y1 = 0.f;
#pragma unroll
    for (int q = 0; q < 16; ++q) {
        float w0 = Wn[(4 * q + 0) * 64 + lane];
        float w1 = Wn[(4 * q + 1) * 64 + lane];
        float w2 = Wn[(4 * q + 2) * 64 + lane];
        float w3 = Wn[(4 * q + 3) * 64 + lane];
        y0 = fmaf(rdlane_f(r0.x, q), w0, y0);
        y0 = fmaf(rdlane_f(r0.y, q), w1, y0);
        y0 = fmaf(rdlane_f(r0.z, q), w2, y0);
        y0 = fmaf(rdlane_f(r0.w, q), w3, y0);
        y1 = fmaf(rdlane_f(r1.x, q), w0, y1);
        y1 = fmaf(rdlane_f(r1.y, q), w1, y1);
        y1 = fmaf(rdlane_f(r1.z, q), w2, y1);
        y1 = fmaf(rdlane_f(r1.w, q), w3, y1);
    }
    Hout[(size_t)i0 * 64 + lane] = f2bf(y0);
    Hout[(size_t)i1 * 64 + lane] = f2bf(y1);
}

// Final layer: interleaved 2-node aggregation only (no ReLU), fp32 d_out.
__global__ __launch_bounds__(256, 8) void k_agg_last(const unsigned short* __restrict__ H,
                                                     const int* __restrict__ row_ptr,
                                                     const long long* __restrict__ csr_ll,
                                                     const float* __restrict__ dinv,
                                                     const float* __restrict__ bias,
                                                     float* __restrict__ out, int N) {
    const int wid  = threadIdx.x >> 6;
    const int lane = threadIdx.x & 63;
    const int i0   = (blockIdx.x * 4 + wid) * 2;
    const int i1   = i0 + 1;
    const int g    = lane >> 4;
    const int c4   = (lane & 15) * 4;

    const float4 b4 = *(const float4*)&bias[c4];

    int idx = i0 + lane;
    int   rp = (lane <= 2) ? row_ptr[idx] : 0;
    float dv = (lane <  2) ? dinv[idx]    : 0.f;
    int s0 = __shfl(rp, 0), sm = __shfl(rp, 1), e1 = __shfl(rp, 2);
    float di0 = __shfl(dv, 0), di1 = __shfl(dv, 1);

    float4 r0, r1;
    agg_row2<false>(H, csr_ll, b4, di0, di1, i0, i1, s0, sm, sm, e1,
                    lane, g, c4, r0, r1);
    if (g == 0) {
        *(float4*)&out[(size_t)i0 * 64 + c4] = r0;
        *(float4*)&out[(size_t)i1 * 64 + c4] = r1;
    }
}

// ---------------- launch ----------------

extern "C" void kernel_launch(void* const* d_in, const int* in_sizes, int n_in,
                              void* d_out, int out_size, void* d_ws, size_t ws_size,
                              hipStream_t stream) {
    (void)in_sizes; (void)n_in; (void)out_size; (void)ws_size;

    const float* x  = (const float*)d_in[0];
    const int*   ei = (const int*)d_in[1];
    const float* Wl[5] = {(const float*)d_in[2], (const float*)d_in[4], (const float*)d_in[6],
                          (const float*)d_in[8], (const float*)d_in[10]};
    const float* bl[5] = {(const float*)d_in[3], (const float*)d_in[5], (const float*)d_in[7],
                          (const float*)d_in[9], (const float*)d_in[11]};
    float* out = (float*)d_out;

    const int* src = ei;
    const int* dst = ei + NE;

    char* ws = (char*)d_ws;
    size_t off = 0;
    auto alloc = [&](size_t bytes) -> void* {
        void* p = ws + off;
        off += (bytes + 255) & ~(size_t)255;
        return p;
    };
    // cnt, cursor contiguous -> single zero pass
    int*   cnt      = (int*)alloc(NN * 4);
    int*   cursor   = (int*)alloc(NN * 4);
    size_t zero_bytes = (size_t)((char*)(cursor + NN) - (char*)cnt);
    int*   row_ptr  = (int*)alloc((NN + 1) * 4);
    int*   bsum     = (int*)alloc(256 * 4);
    float* dinv     = (float*)alloc(NN * 4);
    int2*  csr      = (int2*)alloc((size_t)NE * 8);
    unsigned short* Hb  = (unsigned short*)alloc((size_t)NN * 64 * 2);
    unsigned short* Hb2 = (unsigned short*)alloc((size_t)NN * 64 * 2);

    int n16 = (int)((zero_bytes + 15) / 16);
    k_zero<<<(n16 + 255) / 256, 256, 0, stream>>>((float4*)cnt, n16);

    int ebl = (NE + 255) / 256;
    int nbl = (NN + 255) / 256;
    k_count<<<ebl, 256, 0, stream>>>(dst, cnt, NE);
    k_dinv<<<nbl, 256, 0, stream>>>(cnt, dinv, NN);
    k_scanA<<<nbl, 256, 0, stream>>>(cnt, row_ptr, bsum, NN);
    k_scanB<<<1, 256, 0, stream>>>(bsum, nbl);
    k_scanC<<<nbl, 256, 0, stream>>>(row_ptr, bsum, NN, NE);
    k_fill<<<ebl, 256, 0, stream>>>(src, dst, dinv, row_ptr, cursor, csr, NE);

    const long long* csr_ll = (const long long*)csr;
    int gg = (NN + 63) / 64;
    int ga = NN / 8;    // 6250 blocks x 4 waves x 2 nodes = 50000 exactly

    // layer 1 GEMM (K=128) -> bf16 H
    k_gemm128<<<gg, 256, 0, stream>>>(x, Wl[0], Hb, NN);
    // fused: agg_t (+b_t, ReLU) then @W_{t+1} -> bf16 H
    k_fused<<<ga, 256, 0, stream>>>(Hb,  row_ptr, csr_ll, dinv, bl[0], Wl[1], Hb2, NN);
    k_fused<<<ga, 256, 0, stream>>>(Hb2, row_ptr, csr_ll, dinv, bl[1], Wl[2], Hb,  NN);
    k_fused<<<ga, 256, 0, stream>>>(Hb,  row_ptr, csr_ll, dinv, bl[2], Wl[3], Hb2, NN);
    k_fused<<<ga, 256, 0, stream>>>(Hb2, row_ptr, csr_ll, dinv, bl[3], Wl[4], Hb,  NN);
    // final aggregation (no ReLU) -> fp32 d_out
    k_agg_last<<<ga, 256, 0, stream>>>(Hb, row_ptr, csr_ll, dinv, bl[4], out, NN);
}

// Round 14
// 266.898 us; speedup vs baseline: 1.1089x; 1.0258x over previous
//
#include <hip/hip_runtime.h>
#include <hip/hip_fp16.h>

#define NN 50000
#define NE 800000
#define FILLB ((NE + 255) / 256)   // 3125 fill blocks in the combined kernel

// ---- bf16 helpers ----
__device__ __forceinline__ float bf2f(unsigned short u) {
    union { unsigned int i; float f; } v; v.i = ((unsigned int)u) << 16; return v.f;
}
__device__ __forceinline__ unsigned short f2bf(float f) {
    union { float f; unsigned int i; } v; v.f = f;
    unsigned int r = v.i + 0x7fffu + ((v.i >> 16) & 1u);   // round-to-nearest-even
    return (unsigned short)(r >> 16);
}

// ---------------- workspace zeroing ----------------
__global__ void k_zero(float4* __restrict__ p, int n16) {
    int i = blockIdx.x * 256 + threadIdx.x;
    if (i < n16) p[i] = make_float4(0.f, 0.f, 0.f, 0.f);
}

// ---------------- CSR build ----------------

__global__ void k_count(const int* __restrict__ dst, int* __restrict__ cnt, int E) {
    int e = blockIdx.x * 256 + threadIdx.x;
    if (e < E) atomicAdd(&cnt[dst[e]], 1);
}

__global__ void k_dinv(const int* __restrict__ cnt, float* __restrict__ dinv, int N) {
    int i = blockIdx.x * 256 + threadIdx.x;
    if (i < N) dinv[i] = rsqrtf(2.0f + (float)cnt[i]);
}

__global__ void k_scanA(const int* __restrict__ cnt, int* __restrict__ row_ptr,
                        int* __restrict__ bsum, int N) {
    __shared__ int buf[256];
    int i = blockIdx.x * 256 + threadIdx.x;
    int v = (i < N) ? cnt[i] : 0;
    buf[threadIdx.x] = v;
    __syncthreads();
    for (int off = 1; off < 256; off <<= 1) {
        int t = (threadIdx.x >= off) ? buf[threadIdx.x - off] : 0;
        __syncthreads();
        buf[threadIdx.x] += t;
        __syncthreads();
    }
    if (i < N) row_ptr[i] = buf[threadIdx.x] - v;
    if (threadIdx.x == 255) bsum[blockIdx.x] = buf[255];
}

__global__ void k_scanB(int* __restrict__ bsum, int nb) {
    __shared__ int buf[256];
    int v = (threadIdx.x < nb) ? bsum[threadIdx.x] : 0;
    buf[threadIdx.x] = v;
    __syncthreads();
    for (int off = 1; off < 256; off <<= 1) {
        int t = (threadIdx.x >= off) ? buf[threadIdx.x - off] : 0;
        __syncthreads();
        buf[threadIdx.x] += t;
        __syncthreads();
    }
    if (threadIdx.x < nb) bsum[threadIdx.x] = buf[threadIdx.x] - v;
}

__global__ void k_scanC(int* __restrict__ row_ptr, const int* __restrict__ bsum,
                        int N, int E) {
    int i = blockIdx.x * 256 + threadIdx.x;
    if (i < N) row_ptr[i] += bsum[blockIdx.x];
    if (i == 0) row_ptr[N] = E;
}

// ---------------- Combined: CSR fill (blocks 0..FILLB-1) || layer-1 GEMM ----------------
// R14: the two stages are independent (fill needs scanC's row_ptr; gemm needs
// only x/W1) -> co-schedule the latency-bound scatter with the VALU-bound GEMM.
// csr entry packed to 4B: src(16b, NN<65536) | f16(norm)(16b) — halves the
// scatter writeback AND the per-layer csr stream, and saves a shfl per round.
// Fill path never touches the (statically allocated) LDS; gemm path unchanged
// (#pragma unroll 1 per R1 spill lesson).

__global__ __launch_bounds__(256, 4) void k_fill_gemm(
        const int* __restrict__ src, const int* __restrict__ dst,
        const float* __restrict__ dinv, const int* __restrict__ row_ptr,
        int* __restrict__ cursor, unsigned* __restrict__ csr,
        const float* __restrict__ X, const float* __restrict__ W,
        unsigned short* __restrict__ H, int N) {
    __shared__ float Ws[128 * 64];

    if (blockIdx.x < FILLB) {
        int e = blockIdx.x * 256 + threadIdx.x;
        if (e >= NE) return;
        int s = src[e], d = dst[e];
        int pos = row_ptr[d] + atomicAdd(&cursor[d], 1);
        float nm = dinv[s] * dinv[d];
        csr[pos] = (unsigned)s |
                   ((unsigned)__half_as_ushort(__float2half(nm)) << 16);
        return;
    }

    const int K = 128;
    const int bid = blockIdx.x - FILLB;
    for (int i = threadIdx.x; i < K * 16; i += 256)
        ((float4*)Ws)[i] = ((const float4*)W)[i];
    __syncthreads();

    const int g  = threadIdx.x >> 3;
    const int c0 = (threadIdx.x & 7) * 8;
    const int r0 = bid * 64 + g * 2;
    const int r1 = r0 + 1;
    const bool v0 = r0 < N, v1 = r1 < N;

    float a00=0,a01=0,a02=0,a03=0,a04=0,a05=0,a06=0,a07=0;
    float a10=0,a11=0,a12=0,a13=0,a14=0,a15=0,a16=0,a17=0;

    const float* x0 = X + (size_t)r0 * K;
    const float* x1 = X + (size_t)r1 * K;

#pragma unroll 1
    for (int k0 = 0; k0 < K; k0 += 4) {
        float4 xa = v0 ? *(const float4*)(x0 + k0) : make_float4(0, 0, 0, 0);
        float4 xb = v1 ? *(const float4*)(x1 + k0) : make_float4(0, 0, 0, 0);
#pragma unroll
        for (int kk = 0; kk < 4; ++kk) {
            const float xs0 = (kk == 0) ? xa.x : (kk == 1) ? xa.y : (kk == 2) ? xa.z : xa.w;
            const float xs1 = (kk == 0) ? xb.x : (kk == 1) ? xb.y : (kk == 2) ? xb.z : xb.w;
            const float* wr = &Ws[(k0 + kk) * 64 + c0];
            const float4 w0 = *(const float4*)(wr);
            const float4 w1 = *(const float4*)(wr + 4);
            a00 = fmaf(xs0, w0.x, a00); a01 = fmaf(xs0, w0.y, a01);
            a02 = fmaf(xs0, w0.z, a02); a03 = fmaf(xs0, w0.w, a03);
            a04 = fmaf(xs0, w1.x, a04); a05 = fmaf(xs0, w1.y, a05);
            a06 = fmaf(xs0, w1.z, a06); a07 = fmaf(xs0, w1.w, a07);
            a10 = fmaf(xs1, w0.x, a10); a11 = fmaf(xs1, w0.y, a11);
            a12 = fmaf(xs1, w0.z, a12); a13 = fmaf(xs1, w0.w, a13);
            a14 = fmaf(xs1, w1.x, a14); a15 = fmaf(xs1, w1.y, a15);
            a16 = fmaf(xs1, w1.z, a16); a17 = fmaf(xs1, w1.w, a17);
        }
    }

    if (v0) {
        uint4 p;
        p.x = (unsigned)f2bf(a00) | ((unsigned)f2bf(a01) << 16);
        p.y = (unsigned)f2bf(a02) | ((unsigned)f2bf(a03) << 16);
        p.z = (unsigned)f2bf(a04) | ((unsigned)f2bf(a05) << 16);
        p.w = (unsigned)f2bf(a06) | ((unsigned)f2bf(a07) << 16);
        *(uint4*)&H[(size_t)r0 * 64 + c0] = p;
    }
    if (v1) {
        uint4 p;
        p.x = (unsigned)f2bf(a10) | ((unsigned)f2bf(a11) << 16);
        p.y = (unsigned)f2bf(a12) | ((unsigned)f2bf(a13) << 16);
        p.z = (unsigned)f2bf(a14) | ((unsigned)f2bf(a15) << 16);
        p.w = (unsigned)f2bf(a16) | ((unsigned)f2bf(a17) << 16);
        *(uint4*)&H[(size_t)r1 * 64 + c0] = p;
    }
}

// ---------------- Interleaved 2-node aggregation (bf16 H, packed u32 csr) ----------------
// R11-validated structure; R13-validated zero-LDS tail. u32 csr: one shfl
// broadcasts src+norm together.

__device__ __forceinline__ void unpack(unsigned w, int& ss, float& nn) {
    ss = (int)(w & 0xffffu);
    nn = __half2float(__ushort_as_half((unsigned short)(w >> 16)));
}

template <bool RELU>
__device__ __forceinline__ void agg_row2(const unsigned short* __restrict__ H,
                                         const unsigned* __restrict__ csr,
                                         const float4& b4, float di0, float di1,
                                         int i0, int i1, int s0, int e0, int s1, int e1,
                                         int lane, int g, int c4,
                                         float4& r0, float4& r1) {
    // self-loop rows: issue first, consumed last
    ushort4 hs0 = *(const ushort4*)&H[(size_t)i0 * 64 + c4];
    ushort4 hs1 = *(const ushort4*)&H[(size_t)i1 * 64 + c4];

    // both nodes' csr chunks issued back-to-back (f16 zero bits = 0 -> norm 0)
    int ee0 = s0 + lane, ee1 = s1 + lane;
    unsigned pk0 = (ee0 < e0) ? csr[ee0] : 0u;
    unsigned pk1 = (ee1 < e1) ? csr[ee1] : 0u;

    int m0 = e0 - s0; if (m0 > 64) m0 = 64;
    int m1 = e1 - s1; if (m1 > 64) m1 = 64;
    int nt0 = (m0 + 3) >> 2, nt1 = (m1 + 3) >> 2;
    int ntm = nt0 > nt1 ? nt0 : nt1;

    float4 acc0 = make_float4(0.f, 0.f, 0.f, 0.f);
    float4 acc1 = make_float4(0.f, 0.f, 0.f, 0.f);

#pragma unroll 4
    for (int t = 0; t < ntm; ++t) {      // nt0/nt1 wave-uniform -> shfl safe
        int sl = t * 4 + g;
        if (t < nt0) {
            unsigned w = __shfl(pk0, sl);
            int ss; float nn; unpack(w, ss, nn);
            ushort4 h = *(const ushort4*)&H[(size_t)ss * 64 + c4];
            acc0.x = fmaf(bf2f(h.x), nn, acc0.x);
            acc0.y = fmaf(bf2f(h.y), nn, acc0.y);
            acc0.z = fmaf(bf2f(h.z), nn, acc0.z);
            acc0.w = fmaf(bf2f(h.w), nn, acc0.w);
        }
        if (t < nt1) {
            unsigned w = __shfl(pk1, sl);
            int ss; float nn; unpack(w, ss, nn);
            ushort4 h = *(const ushort4*)&H[(size_t)ss * 64 + c4];
            acc1.x = fmaf(bf2f(h.x), nn, acc1.x);
            acc1.y = fmaf(bf2f(h.y), nn, acc1.y);
            acc1.z = fmaf(bf2f(h.z), nn, acc1.z);
            acc1.w = fmaf(bf2f(h.w), nn, acc1.w);
        }
    }

    // rare deg>64 spill chunks, sequential
    for (int base = s0 + 64; base < e0; base += 64) {
        int e = base + lane;
        unsigned pk = (e < e0) ? csr[e] : 0u;
        int m = e0 - base; if (m > 64) m = 64;
        int nt = (m + 3) >> 2;
        for (int t = 0; t < nt; ++t) {
            unsigned w = __shfl(pk, t * 4 + g);
            int ss; float nn; unpack(w, ss, nn);
            ushort4 h = *(const ushort4*)&H[(size_t)ss * 64 + c4];
            acc0.x = fmaf(bf2f(h.x), nn, acc0.x);
            acc0.y = fmaf(bf2f(h.y), nn, acc0.y);
            acc0.z = fmaf(bf2f(h.z), nn, acc0.z);
            acc0.w = fmaf(bf2f(h.w), nn, acc0.w);
        }
    }
    for (int base = s1 + 64; base < e1; base += 64) {
        int e = base + lane;
        unsigned pk = (e < e1) ? csr[e] : 0u;
        int m = e1 - base; if (m > 64) m = 64;
        int nt = (m + 3) >> 2;
        for (int t = 0; t < nt; ++t) {
            unsigned w = __shfl(pk, t * 4 + g);
            int ss; float nn; unpack(w, ss, nn);
            ushort4 h = *(const ushort4*)&H[(size_t)ss * 64 + c4];
            acc1.x = fmaf(bf2f(h.x), nn, acc1.x);
            acc1.y = fmaf(bf2f(h.y), nn, acc1.y);
            acc1.z = fmaf(bf2f(h.z), nn, acc1.z);
            acc1.w = fmaf(bf2f(h.w), nn, acc1.w);
        }
    }

#pragma unroll
    for (int d = 16; d <= 32; d <<= 1) {
        acc0.x += __shfl_xor(acc0.x, d); acc0.y += __shfl_xor(acc0.y, d);
        acc0.z += __shfl_xor(acc0.z, d); acc0.w += __shfl_xor(acc0.w, d);
        acc1.x += __shfl_xor(acc1.x, d); acc1.y += __shfl_xor(acc1.y, d);
        acc1.z += __shfl_xor(acc1.z, d); acc1.w += __shfl_xor(acc1.w, d);
    }

    float sa = 2.0f * di0 * di0, sb = 2.0f * di1 * di1;
    r0.x = acc0.x + sa * bf2f(hs0.x) + b4.x;
    r0.y = acc0.y + sa * bf2f(hs0.y) + b4.y;
    r0.z = acc0.z + sa * bf2f(hs0.z) + b4.z;
    r0.w = acc0.w + sa * bf2f(hs0.w) + b4.w;
    r1.x = acc1.x + sb * bf2f(hs1.x) + b4.x;
    r1.y = acc1.y + sb * bf2f(hs1.y) + b4.y;
    r1.z = acc1.z + sb * bf2f(hs1.z) + b4.z;
    r1.w = acc1.w + sb * bf2f(hs1.w) + b4.w;
    if (RELU) {
        r0.x = fmaxf(r0.x, 0.f); r0.y = fmaxf(r0.y, 0.f);
        r0.z = fmaxf(r0.z, 0.f); r0.w = fmaxf(r0.w, 0.f);
        r1.x = fmaxf(r1.x, 0.f); r1.y = fmaxf(r1.y, 0.f);
        r1.z = fmaxf(r1.z, 0.f); r1.w = fmaxf(r1.w, 0.f);
    }
}

__device__ __forceinline__ float rdlane_f(float x, int l) {
    return __uint_as_float(__builtin_amdgcn_readlane(__float_as_uint(x), l));
}

// Fused: A = ReLU(S*H + b) for 2 nodes, then both @ Wn; Hout bf16.
// Zero LDS, zero barriers (R13); W read global-coalesced in the tail.
__global__ __launch_bounds__(256, 8) void k_fused(const unsigned short* __restrict__ H,
                                                  const int* __restrict__ row_ptr,
                                                  const unsigned* __restrict__ csr,
                                                  const float* __restrict__ dinv,
                                                  const float* __restrict__ bias,
                                                  const float* __restrict__ Wn,
                                                  unsigned short* __restrict__ Hout, int N) {
    const int wid  = threadIdx.x >> 6;
    const int lane = threadIdx.x & 63;
    const int i0   = (blockIdx.x * 4 + wid) * 2;
    const int i1   = i0 + 1;
    const int g    = lane >> 4;
    const int c4   = (lane & 15) * 4;

    int idx = i0 + lane;
    int   rp = (lane <= 2) ? row_ptr[idx] : 0;
    float dv = (lane <  2) ? dinv[idx]    : 0.f;

    const float4 b4 = *(const float4*)&bias[c4];
    int s0 = __shfl(rp, 0), sm = __shfl(rp, 1), e1 = __shfl(rp, 2);
    float di0 = __shfl(dv, 0), di1 = __shfl(dv, 1);

    float4 r0, r1;
    agg_row2<true>(H, csr, b4, di0, di1, i0, i1, s0, sm, sm, e1,
                   lane, g, c4, r0, r1);

    // tail GEMM: channel 4q+k lives in lane q; W column shared by both nodes
    float y0 = 0.f, y1 = 0.f;
#pragma unroll
    for (int q = 0; q < 16; ++q) {
        float w0 = Wn[(4 * q + 0) * 64 + lane];
        float w1 = Wn[(4 * q + 1) * 64 + lane];
        float w2 = Wn[(4 * q + 2) * 64 + lane];
        float w3 = Wn[(4 * q + 3) * 64 + lane];
        y0 = fmaf(rdlane_f(r0.x, q), w0, y0);
        y0 = fmaf(rdlane_f(r0.y, q), w1, y0);
        y0 = fmaf(rdlane_f(r0.z, q), w2, y0);
        y0 = fmaf(rdlane_f(r0.w, q), w3, y0);
        y1 = fmaf(rdlane_f(r1.x, q), w0, y1);
        y1 = fmaf(rdlane_f(r1.y, q), w1, y1);
        y1 = fmaf(rdlane_f(r1.z, q), w2, y1);
        y1 = fmaf(rdlane_f(r1.w, q), w3, y1);
    }
    Hout[(size_t)i0 * 64 + lane] = f2bf(y0);
    Hout[(size_t)i1 * 64 + lane] = f2bf(y1);
}

// Final layer: interleaved 2-node aggregation only (no ReLU), fp32 d_out.
__global__ __launch_bounds__(256, 8) void k_agg_last(const unsigned short* __restrict__ H,
                                                     const int* __restrict__ row_ptr,
                                                     const unsigned* __restrict__ csr,
                                                     const float* __restrict__ dinv,
                                                     const float* __restrict__ bias,
                                                     float* __restrict__ out, int N) {
    const int wid  = threadIdx.x >> 6;
    const int lane = threadIdx.x & 63;
    const int i0   = (blockIdx.x * 4 + wid) * 2;
    const int i1   = i0 + 1;
    const int g    = lane >> 4;
    const int c4   = (lane & 15) * 4;

    const float4 b4 = *(const float4*)&bias[c4];

    int idx = i0 + lane;
    int   rp = (lane <= 2) ? row_ptr[idx] : 0;
    float dv = (lane <  2) ? dinv[idx]    : 0.f;
    int s0 = __shfl(rp, 0), sm = __shfl(rp, 1), e1 = __shfl(rp, 2);
    float di0 = __shfl(dv, 0), di1 = __shfl(dv, 1);

    float4 r0, r1;
    agg_row2<false>(H, csr, b4, di0, di1, i0, i1, s0, sm, sm, e1,
                    lane, g, c4, r0, r1);
    if (g == 0) {
        *(float4*)&out[(size_t)i0 * 64 + c4] = r0;
        *(float4*)&out[(size_t)i1 * 64 + c4] = r1;
    }
}

// ---------------- launch ----------------

extern "C" void kernel_launch(void* const* d_in, const int* in_sizes, int n_in,
                              void* d_out, int out_size, void* d_ws, size_t ws_size,
                              hipStream_t stream) {
    (void)in_sizes; (void)n_in; (void)out_size; (void)ws_size;

    const float* x  = (const float*)d_in[0];
    const int*   ei = (const int*)d_in[1];
    const float* Wl[5] = {(const float*)d_in[2], (const float*)d_in[4], (const float*)d_in[6],
                          (const float*)d_in[8], (const float*)d_in[10]};
    const float* bl[5] = {(const float*)d_in[3], (const float*)d_in[5], (const float*)d_in[7],
                          (const float*)d_in[9], (const float*)d_in[11]};
    float* out = (float*)d_out;

    const int* src = ei;
    const int* dst = ei + NE;

    char* ws = (char*)d_ws;
    size_t off = 0;
    auto alloc = [&](size_t bytes) -> void* {
        void* p = ws + off;
        off += (bytes + 255) & ~(size_t)255;
        return p;
    };
    // cnt, cursor contiguous -> single zero pass
    int*      cnt     = (int*)alloc(NN * 4);
    int*      cursor  = (int*)alloc(NN * 4);
    size_t zero_bytes = (size_t)((char*)(cursor + NN) - (char*)cnt);
    int*      row_ptr = (int*)alloc((NN + 1) * 4);
    int*      bsum    = (int*)alloc(256 * 4);
    float*    dinv    = (float*)alloc(NN * 4);
    unsigned* csr     = (unsigned*)alloc((size_t)NE * 4);
    unsigned short* Hb  = (unsigned short*)alloc((size_t)NN * 64 * 2);
    unsigned short* Hb2 = (unsigned short*)alloc((size_t)NN * 64 * 2);

    int n16 = (int)((zero_bytes + 15) / 16);
    k_zero<<<(n16 + 255) / 256, 256, 0, stream>>>((float4*)cnt, n16);

    int ebl = (NE + 255) / 256;
    int nbl = (NN + 255) / 256;
    int gg  = (NN + 63) / 64;
    k_count<<<ebl, 256, 0, stream>>>(dst, cnt, NE);
    k_dinv<<<nbl, 256, 0, stream>>>(cnt, dinv, NN);
    k_scanA<<<nbl, 256, 0, stream>>>(cnt, row_ptr, bsum, NN);
    k_scanB<<<1, 256, 0, stream>>>(bsum, nbl);
    k_scanC<<<nbl, 256, 0, stream>>>(row_ptr, bsum, NN, NE);
    // fill || layer-1 GEMM (independent stages co-scheduled)
    k_fill_gemm<<<FILLB + gg, 256, 0, stream>>>(src, dst, dinv, row_ptr, cursor,
                                                csr, x, Wl[0], Hb, NN);

    int ga = NN / 8;    // 6250 blocks x 4 waves x 2 nodes = 50000 exactly

    // fused: agg_t (+b_t, ReLU) then @W_{t+1} -> bf16 H
    k_fused<<<ga, 256, 0, stream>>>(Hb,  row_ptr, csr, dinv, bl[0], Wl[1], Hb2, NN);
    k_fused<<<ga, 256, 0, stream>>>(Hb2, row_ptr, csr, dinv, bl[1], Wl[2], Hb,  NN);
    k_fused<<<ga, 256, 0, stream>>>(Hb,  row_ptr, csr, dinv, bl[2], Wl[3], Hb2, NN);
    k_fused<<<ga, 256, 0, stream>>>(Hb2, row_ptr, csr, dinv, bl[3], Wl[4], Hb,  NN);
    // final aggregation (no ReLU) -> fp32 d_out
    k_agg_last<<<ga, 256, 0, stream>>>(Hb, row_ptr, csr, dinv, bl[4], out, NN);
}